// Round 6
// baseline (350.143 us; speedup 1.0000x reference)
//
#include <hip/hip_runtime.h>

typedef __bf16 bf16x8 __attribute__((ext_vector_type(8)));
typedef float f32x4 __attribute__((ext_vector_type(4)));
typedef float f32x16 __attribute__((ext_vector_type(16)));
typedef unsigned short u16;
typedef unsigned long long u64;

static constexpr int D = 256;      // feature dim
static constexpr int BROWS = 2048; // batch per view
static constexpr int QN = 65536;   // queue rows

__device__ __forceinline__ f32x4 mfma16(bf16x8 a, bf16x8 b, f32x4 c) {
  return __builtin_amdgcn_mfma_f32_16x16x32_bf16(a, b, c, 0, 0, 0);
}
__device__ __forceinline__ f32x16 mfma32(bf16x8 a, bf16x8 b, f32x16 c) {
  return __builtin_amdgcn_mfma_f32_32x32x16_bf16(a, b, c, 0, 0, 0);
}
__device__ __forceinline__ u16 bfb(float f) { return __builtin_bit_cast(u16, (__bf16)f); }

// ---- LDS staging, [ROWS][256] bf16 row-major, XOR swizzle ((row&7)<<4) ----
template<int ROWS>
__device__ __forceinline__ void stage_bf16(const u16* __restrict__ src, u16* lds, int tid) {
#pragma unroll
  for (int i = 0; i < ROWS / 8; ++i) {
    int slot = i * 256 + tid;
    int row = slot >> 5, s = slot & 31;
    bf16x8 d = *reinterpret_cast<const bf16x8*>(src + (size_t)row * D + s * 8);
    int byt = (row * 512 + s * 16) ^ ((row & 7) << 4);
    *reinterpret_cast<bf16x8*>(reinterpret_cast<char*>(lds) + byt) = d;
  }
}

template<int ROWS>
__device__ __forceinline__ void stage_f32(const float* __restrict__ src, u16* lds, int tid) {
#pragma unroll
  for (int i = 0; i < ROWS / 8; ++i) {
    int slot = i * 256 + tid;
    int row = slot >> 5, s = slot & 31;
    const float* p = src + (size_t)row * D + s * 8;
    float4 q0 = *reinterpret_cast<const float4*>(p);
    float4 q1 = *reinterpret_cast<const float4*>(p + 4);
    bf16x8 h;
    h[0] = (__bf16)q0.x; h[1] = (__bf16)q0.y; h[2] = (__bf16)q0.z; h[3] = (__bf16)q0.w;
    h[4] = (__bf16)q1.x; h[5] = (__bf16)q1.y; h[6] = (__bf16)q1.z; h[7] = (__bf16)q1.w;
    int byt = (row * 512 + s * 16) ^ ((row & 7) << 4);
    *reinterpret_cast<bf16x8*>(reinterpret_cast<char*>(lds) + byt) = h;
  }
}

__device__ __forceinline__ bf16x8 fragld(const u16* lds, int row, int ks, int lane) {
  int byt = (row * 512 + ((ks * 64 + ((lane >> 4) << 4)) ^ ((row & 7) << 4)));
  return *reinterpret_cast<const bf16x8*>(reinterpret_cast<const char*>(lds) + byt);
}

// ---- 1. transpose+convert W [k][n] f32 -> Wt [n][k] bf16 ----
__global__ void wt_convert(const float* __restrict__ W1, const float* __restrict__ W2,
                           u16* __restrict__ Wt) {
  const float* W = blockIdx.x == 0 ? W1 : W2;
  u16* o = Wt + blockIdx.x * 65536;
  for (int i = threadIdx.x; i < 65536; i += 256) {
    int k = i >> 8, n = i & 255;
    o[n * 256 + k] = bfb(W[i]);
  }
}

// ---- 2. projection layer GEMM: out = act(A @ W + b), M=4096 N=256 K=256 ----
template<bool SRC_F32, bool RELU>
__global__ __launch_bounds__(256) void proj_kernel(
    const float* __restrict__ h1, const float* __restrict__ h2,
    const u16* __restrict__ Asrc, const u16* __restrict__ Wt,
    const float* __restrict__ bias, u16* __restrict__ out_bf,
    float* __restrict__ out_f32) {
  __shared__ u16 Alds[128 * 256];
  __shared__ u16 Blds[128 * 256];
  int tid = threadIdx.x;
  int r0 = blockIdx.y * 128, n0 = blockIdx.x * 128;
  if constexpr (SRC_F32) {
    const float* src = (r0 < BROWS) ? (h1 + (size_t)r0 * D) : (h2 + (size_t)(r0 - BROWS) * D);
    stage_f32<128>(src, Alds, tid);
  } else {
    stage_bf16<128>(Asrc + (size_t)r0 * D, Alds, tid);
  }
  stage_bf16<128>(Wt + (size_t)n0 * D, Blds, tid);
  __syncthreads();

  int lane = tid & 63, w = tid >> 6, wm = w >> 1, wn = w & 1;
  f32x4 acc[4][4];
  const f32x4 vz = {0.f, 0.f, 0.f, 0.f};
#pragma unroll
  for (int m = 0; m < 4; ++m)
#pragma unroll
    for (int n = 0; n < 4; ++n) acc[m][n] = vz;

#pragma unroll
  for (int ks = 0; ks < 8; ++ks) {
    bf16x8 a[4], b[4];
#pragma unroll
    for (int i = 0; i < 4; ++i) a[i] = fragld(Alds, wm * 64 + i * 16 + (lane & 15), ks, lane);
#pragma unroll
    for (int i = 0; i < 4; ++i) b[i] = fragld(Blds, wn * 64 + i * 16 + (lane & 15), ks, lane);
#pragma unroll
    for (int m = 0; m < 4; ++m)
#pragma unroll
      for (int n = 0; n < 4; ++n) acc[m][n] = mfma16(a[m], b[n], acc[m][n]);
  }

#pragma unroll
  for (int m = 0; m < 4; ++m)
#pragma unroll
    for (int n = 0; n < 4; ++n)
#pragma unroll
      for (int j = 0; j < 4; ++j) {
        int row = r0 + wm * 64 + m * 16 + ((lane >> 4) << 2) + j;
        int col = n0 + wn * 64 + n * 16 + (lane & 15);
        float v = acc[m][n][j] + bias[col];
        if constexpr (RELU) {
          v = fmaxf(v, 0.f);
          out_bf[(size_t)row * D + col] = bfb(v);
        } else {
          out_f32[(size_t)row * D + col] = v;
        }
      }
}

// ---- 3. row L2-normalize (+ zero the argmax table for the next kernel) ----
__global__ void normalize_k(const float* __restrict__ Z, u16* __restrict__ ZNb,
                            float* __restrict__ outq, u64* __restrict__ tab) {
  if (blockIdx.x < 16) tab[blockIdx.x * 256 + threadIdx.x] = 0ull;
  int row = blockIdx.x * 4 + (threadIdx.x >> 6);
  int lane = threadIdx.x & 63;
  float4 v = *reinterpret_cast<const float4*>(Z + (size_t)row * D + lane * 4);
  float ss = v.x * v.x + v.y * v.y + v.z * v.z + v.w * v.w;
#pragma unroll
  for (int m = 1; m <= 32; m <<= 1) ss += __shfl_xor(ss, m, 64);
  float s = 1.f / fmaxf(sqrtf(ss), 1e-12f);
  float ox = v.x * s, oy = v.y * s, oz = v.z * s, ow = v.w * s;
  u64 pk = (u64)bfb(ox) | ((u64)bfb(oy) << 16) | ((u64)bfb(oz) << 32) | ((u64)bfb(ow) << 48);
  *reinterpret_cast<u64*>(ZNb + (size_t)row * D + lane * 4) = pk;
  if (row < BROWS) {
    float* p = outq + (size_t)row * D + lane * 4;
    p[0] = ox; p[1] = oy; p[2] = oz; p[3] = ow;
  }
}

// ---- 4. NN search (32x32x16, swapped operands) + in-loop FIFO copy ----
// grid (256,2). 2-chunk phases: 2 x 32KB buffers, 32 iters, 64 rows/phase.
// Per iter per wave VMEM FIFO: [stage next pair: 8][copy load: 1] -> wait
// vmcnt(12) (9 on iter 0) -> barrier -> [chunk A: 32 mfma + argmax + atomic]
// [copy store: 1][chunk B: ... + atomic] -> barrier. Row argmax result goes
// straight to a u64 atomicMax table (masked-f32 | global col) -> no nkey
// array. Copy: each thread moves exactly 1 float4/iter (512 blk x 32 x 256
// x 16B = 64MB, clamped tail).
__global__ __launch_bounds__(256, 2) void nn_gemm(const float* __restrict__ queue,
                                                  const u16* __restrict__ ZNb,
                                                  u64* __restrict__ tab,
                                                  float* __restrict__ copydst) {
  __shared__ char Abuf[2][32768];
  const int tid = threadIdx.x, lane = tid & 63, w = tid >> 6;
  const int bx = blockIdx.x, by = blockIdx.y;
  const int colbase = bx * 256 + w * 64;
  const int rowid = lane & 31, sl0 = lane >> 5;

  // queue cols -> regs as 32x32x16 A-operand frags
  bf16x8 bq[2][16];
#pragma unroll
  for (int t = 0; t < 2; ++t)
#pragma unroll
    for (int ks = 0; ks < 16; ++ks) {
      const float* p = queue + (size_t)(colbase + t * 32 + rowid) * D + ks * 16 + sl0 * 8;
      float4 q0 = *reinterpret_cast<const float4*>(p);
      float4 q1 = *reinterpret_cast<const float4*>(p + 4);
      bf16x8 h;
      h[0] = (__bf16)q0.x; h[1] = (__bf16)q0.y; h[2] = (__bf16)q0.z; h[3] = (__bf16)q0.w;
      h[4] = (__bf16)q1.x; h[5] = (__bf16)q1.y; h[6] = (__bf16)q1.z; h[7] = (__bf16)q1.w;
      bq[t][ks] = h;
    }

  // global source offsets with INVERSE 5-bit swizzle (LDS dest linear).
  // dest r = w*16 + c*2 + (lane>>5) in the 64-row pair, slot = lane&31.
  int goff[8];
#pragma unroll
  for (int c = 0; c < 8; ++c) {
    int r = w * 16 + c * 2 + sl0;
    int s = lane & 31;
    goff[c] = r * 512 + ((s ^ (r & 31)) << 4);
  }

  const char* gbase = (const char*)ZNb + (size_t)by * 1048576;

  // prologue: stage pair 0 into buf0; first copy element
#pragma unroll
  for (int c = 0; c < 8; ++c)
    __builtin_amdgcn_global_load_lds((const unsigned*)(gbase + goff[c]),
                                     (unsigned*)(Abuf[0] + w * 8192 + c * 1024), 16, 0, 0);
  const size_t N4 = (size_t)(QN - BROWS) * D / 4;  // 4,063,232 float4
  const size_t cbase4 = ((size_t)(by * 256 + bx)) * 8192 + (size_t)tid;
  size_t ci = cbase4 < N4 - 1 ? cbase4 : N4 - 1;
  float4 ccur = reinterpret_cast<const float4*>(queue)[ci];

#define DO_CHUNK(CB, GCHUNK)                                                              \
  do {                                                                                    \
    f32x16 a0, a1;                                                                        \
    _Pragma("unroll") for (int j = 0; j < 16; ++j) { a0[j] = 4.f; a1[j] = 4.f; }          \
    const char* base_ = (CB) + rowid * 512;                                               \
    __builtin_amdgcn_s_setprio(1);                                                        \
    _Pragma("unroll") for (int ks = 0; ks < 16; ++ks) {                                   \
      bf16x8 rf = *reinterpret_cast<const bf16x8*>(base_ + ((((ks << 1) + sl0) ^ rowid) << 4)); \
      a0 = mfma32(bq[0][ks], rf, a0);                                                     \
      a1 = mfma32(bq[1][ks], rf, a1);                                                     \
    }                                                                                     \
    __builtin_amdgcn_s_setprio(0);                                                        \
    unsigned best = 0u;                                                                   \
    _Pragma("unroll") for (int j = 0; j < 16; ++j) {                                      \
      unsigned id = (unsigned)((sl0 << 2) + (j & 3) + ((j >> 2) << 3));                   \
      unsigned va = (__float_as_uint(a0[j]) & 0xFFFFFFC0u) | id;                          \
      unsigned vb = (__float_as_uint(a1[j]) & 0xFFFFFFC0u) | (id + 32u);                  \
      best = va > best ? va : best;                                                       \
      best = vb > best ? vb : best;                                                       \
    }                                                                                     \
    unsigned o_ = (unsigned)__shfl_xor((int)best, 32, 64);                                \
    if (o_ > best) best = o_;                                                             \
    if (lane < 32) {                                                                      \
      u64 key = ((u64)best << 32) | (u64)(unsigned)(colbase + (int)(best & 63u));         \
      atomicMax((unsigned long long*)&tab[(size_t)(GCHUNK)*32 + lane],                    \
                (unsigned long long)key);                                                 \
    }                                                                                     \
  } while (0)

  for (int i = 0; i < 32; ++i) {
    // stage next pair ((i+1)&31 keeps it in-bounds; iter-31 restage unread)
    {
      const char* g = gbase + (size_t)((i + 1) & 31) * 32768;
      char* dstb = Abuf[(i + 1) & 1] + w * 8192;
#pragma unroll
      for (int c = 0; c < 8; ++c)
        __builtin_amdgcn_global_load_lds((const unsigned*)(g + goff[c]),
                                         (unsigned*)(dstb + c * 1024), 16, 0, 0);
    }
    size_t ni = cbase4 + (size_t)(i + 1) * 256;
    ni = ni < N4 - 1 ? ni : N4 - 1;
    float4 cnxt = reinterpret_cast<const float4*>(queue)[ni];

    __builtin_amdgcn_sched_barrier(0);
    if (i == 0) {
      asm volatile("s_waitcnt vmcnt(9)" ::: "memory");
    } else {
      asm volatile("s_waitcnt vmcnt(12)" ::: "memory");
    }
    __builtin_amdgcn_s_barrier();
    __builtin_amdgcn_sched_barrier(0);

    const char* pb = Abuf[i & 1];
    DO_CHUNK(pb, by * 64 + 2 * i);
    {
      size_t si = cbase4 + (size_t)i * 256;
      si = si < N4 - 1 ? si : N4 - 1;
      reinterpret_cast<float4*>(copydst)[si] = ccur;
    }
    DO_CHUNK(pb + 16384, by * 64 + 2 * i + 1);

    __builtin_amdgcn_sched_barrier(0);
    __builtin_amdgcn_s_barrier();
    ccur = cnxt;
  }
#undef DO_CHUNK
}

// ---- 5. gather: best col per row from atomic table -> NNb bf16 ----
__global__ void nn_finish(const u64* __restrict__ tab, const float* __restrict__ queue,
                          u16* __restrict__ NNb) {
  int row = blockIdx.x * 4 + (threadIdx.x >> 6);
  int lane = threadIdx.x & 63;
  u64 t = tab[row];
  int idx = (int)(unsigned)(t & 0xFFFFFFFFull);
  float4 v = *(reinterpret_cast<const float4*>(queue + (size_t)idx * D) + lane);
  u64 pk = (u64)bfb(v.x) | ((u64)bfb(v.y) << 16) | ((u64)bfb(v.z) << 32) | ((u64)bfb(v.w) << 48);
  *reinterpret_cast<u64*>(NNb + (size_t)row * D + lane * 4) = pk;
}

// ---- 7. CE logits GEMM with fused row/col softmax partials + diag ----
__global__ __launch_bounds__(256) void ce_gemm(const u16* __restrict__ NNb,
                                               const u16* __restrict__ ZNb,
                                               float2* __restrict__ rowpart,
                                               float2* __restrict__ colpart,
                                               float* __restrict__ diag) {
  __shared__ u16 Alds[128 * 256];
  __shared__ u16 Blds[128 * 256];
  int tid = threadIdx.x;
  int cb = blockIdx.x, rb = blockIdx.y, mat = blockIdx.z;
  const u16* A = NNb + (size_t)(mat * BROWS + rb * 128) * D;
  const u16* Bm = ZNb + (size_t)((mat == 0 ? BROWS : 0) + cb * 128) * D;
  stage_bf16<128>(A, Alds, tid);
  stage_bf16<128>(Bm, Blds, tid);
  __syncthreads();

  int lane = tid & 63, w = tid >> 6, wm = w >> 1, wn = w & 1;
  f32x4 acc[4][4];
  const f32x4 vz = {0.f, 0.f, 0.f, 0.f};
#pragma unroll
  for (int m = 0; m < 4; ++m)
#pragma unroll
    for (int n = 0; n < 4; ++n) acc[m][n] = vz;

#pragma unroll
  for (int ks = 0; ks < 8; ++ks) {
    bf16x8 a[4], b[4];
#pragma unroll
    for (int i = 0; i < 4; ++i) a[i] = fragld(Alds, wm * 64 + i * 16 + (lane & 15), ks, lane);
#pragma unroll
    for (int i = 0; i < 4; ++i) b[i] = fragld(Blds, wn * 64 + i * 16 + (lane & 15), ks, lane);
#pragma unroll
    for (int m = 0; m < 4; ++m)
#pragma unroll
      for (int n = 0; n < 4; ++n) acc[m][n] = mfma16(a[m], b[n], acc[m][n]);
  }

#pragma unroll
  for (int m = 0; m < 4; ++m)
#pragma unroll
    for (int n = 0; n < 4; ++n) acc[m][n] = acc[m][n] * 10.f;  // 1/TEMP

  int rbase = rb * 128 + wm * 64;
  int cbase = cb * 128 + wn * 64;

#pragma unroll
  for (int m = 0; m < 4; ++m)
#pragma unroll
    for (int j = 0; j < 4; ++j) {
      float mx = -3e38f;
#pragma unroll
      for (int n = 0; n < 4; ++n) mx = fmaxf(mx, acc[m][n][j]);
#pragma unroll
      for (int s = 1; s <= 8; s <<= 1) mx = fmaxf(mx, __shfl_xor(mx, s, 64));
      float sm = 0.f;
#pragma unroll
      for (int n = 0; n < 4; ++n) sm += __expf(acc[m][n][j] - mx);
#pragma unroll
      for (int s = 1; s <= 8; s <<= 1) sm += __shfl_xor(sm, s, 64);
      if ((lane & 15) == 0) {
        int r = rbase + m * 16 + ((lane >> 4) << 2) + j;
        rowpart[(((size_t)mat * BROWS + r) << 5) + cb * 2 + wn] = make_float2(mx, sm);
      }
    }

#pragma unroll
  for (int n = 0; n < 4; ++n) {
    float mx = -3e38f;
#pragma unroll
    for (int m = 0; m < 4; ++m)
#pragma unroll
      for (int j = 0; j < 4; ++j) mx = fmaxf(mx, acc[m][n][j]);
#pragma unroll
    for (int s = 16; s <= 32; s <<= 1) mx = fmaxf(mx, __shfl_xor(mx, s, 64));
    float sm = 0.f;
#pragma unroll
    for (int m = 0; m < 4; ++m)
#pragma unroll
      for (int j = 0; j < 4; ++j) sm += __expf(acc[m][n][j] - mx);
#pragma unroll
    for (int s = 16; s <= 32; s <<= 1) sm += __shfl_xor(sm, s, 64);
    if (lane < 16) {
      int c = cbase + n * 16 + lane;
      colpart[(((size_t)mat * BROWS + c) << 5) + rb * 2 + wm] = make_float2(mx, sm);
    }
  }

#pragma unroll
  for (int m = 0; m < 4; ++m)
#pragma unroll
    for (int n = 0; n < 4; ++n)
#pragma unroll
      for (int j = 0; j < 4; ++j) {
        int rg = rbase + m * 16 + ((lane >> 4) << 2) + j;
        int cg = cbase + n * 16 + (lane & 15);
        if (rg == cg) diag[mat * BROWS + rg] = acc[m][n][j];
      }
}

// ---- 8a. per-64-row loss partials (64 blocks) ----
__global__ void loss_part(const float2* __restrict__ rowpart, const float2* __restrict__ colpart,
                          const float* __restrict__ diag, float* __restrict__ lpart) {
  __shared__ float red[256];
  int tid = threadIdx.x;
  int r = blockIdx.x * 64 + (tid >> 2), q = tid & 3;
  const float2* rp = rowpart + ((size_t)r << 5) + q * 8;
  float2 e[8];
#pragma unroll
  for (int i = 0; i < 8; ++i) e[i] = rp[i];
  float mx = e[0].x;
#pragma unroll
  for (int i = 1; i < 8; ++i) mx = fmaxf(mx, e[i].x);
  mx = fmaxf(mx, __shfl_xor(mx, 1, 64));
  mx = fmaxf(mx, __shfl_xor(mx, 2, 64));
  float s = 0.f;
#pragma unroll
  for (int i = 0; i < 8; ++i) s += e[i].y * __expf(e[i].x - mx);
  s += __shfl_xor(s, 1, 64);
  s += __shfl_xor(s, 2, 64);
  float rlse = mx + __logf(s);

  const float2* cp = colpart + ((size_t)r << 5) + q * 8;
#pragma unroll
  for (int i = 0; i < 8; ++i) e[i] = cp[i];
  float mx2 = e[0].x;
#pragma unroll
  for (int i = 1; i < 8; ++i) mx2 = fmaxf(mx2, e[i].x);
  mx2 = fmaxf(mx2, __shfl_xor(mx2, 1, 64));
  mx2 = fmaxf(mx2, __shfl_xor(mx2, 2, 64));
  float s2 = 0.f;
#pragma unroll
  for (int i = 0; i < 8; ++i) s2 += e[i].y * __expf(e[i].x - mx2);
  s2 += __shfl_xor(s2, 1, 64);
  s2 += __shfl_xor(s2, 2, 64);
  float clse = mx2 + __logf(s2);

  red[tid] = (q == 0) ? (rlse + clse - 2.f * diag[r]) : 0.f;
  __syncthreads();
  for (int st = 128; st > 0; st >>= 1) {
    if (tid < st) red[tid] += red[tid + st];
    __syncthreads();
  }
  if (tid == 0) lpart[blockIdx.x] = red[0];
}

// ---- 8b. final scalar ----
__global__ void loss_final(const float* __restrict__ lpart, float* __restrict__ out) {
  int lane = threadIdx.x;
  float v = lpart[lane];
#pragma unroll
  for (int m = 1; m <= 32; m <<= 1) v += __shfl_xor(v, m, 64);
  if (lane == 0) out[0] = v * (1.f / 8192.f);
}

extern "C" void kernel_launch(void* const* d_in, const int* in_sizes, int n_in,
                              void* d_out, int out_size, void* d_ws, size_t ws_size,
                              hipStream_t stream) {
  const float* h1 = (const float*)d_in[0];
  const float* h2 = (const float*)d_in[1];
  const float* W1 = (const float*)d_in[2];
  const float* b1 = (const float*)d_in[3];
  const float* W2 = (const float*)d_in[4];
  const float* b2 = (const float*)d_in[5];
  const float* fq = (const float*)d_in[6];
  float* out = (float*)d_out;

  char* ws = (char*)d_ws;
  u16* Wt        = (u16*)(ws);                        // [2][256][256] bf16   (256 KB)
  u16* Ybf       = (u16*)(ws + 262144);               // [4096][256] bf16     (2 MB)
  float* Z       = (float*)(ws + 2359296);            // [4096][256] f32      (4 MB)
  u16* ZNb       = (u16*)(ws + 6553600);              // [4096][256] bf16     (2 MB)
  u64* tab       = (u64*)(ws + 8650752);              // [4096] u64 argmax    (32 KB)
  u16* NNb       = (u16*)(ws + 25444352);             // [4096][256] bf16     (2 MB)
  float2* rowp   = (float2*)(ws + 27541504);          // [2][2048][32]        (1 MB)
  float2* colp   = (float2*)(ws + 28590080);          // [2][2048][32]        (1 MB)
  float* diag    = (float*)(ws + 29638656);           // [2][2048]
  float* lpart   = (float*)(ws + 29655040);           // [64]

  wt_convert<<<dim3(2), dim3(256), 0, stream>>>(W1, W2, Wt);
  proj_kernel<true, true><<<dim3(2, 32), dim3(256), 0, stream>>>(
      h1, h2, (const u16*)nullptr, Wt, b1, Ybf, (float*)nullptr);
  proj_kernel<false, false><<<dim3(2, 32), dim3(256), 0, stream>>>(
      (const float*)nullptr, (const float*)nullptr, Ybf, Wt + 65536, b2, (u16*)nullptr, Z);
  normalize_k<<<dim3(1024), dim3(256), 0, stream>>>(Z, ZNb, out + 1, tab);
  nn_gemm<<<dim3(256, 2), dim3(256), 0, stream>>>(fq, ZNb, tab,
                                                  out + 1 + (size_t)BROWS * D);
  nn_finish<<<dim3(1024), dim3(256), 0, stream>>>(tab, fq, NNb);
  ce_gemm<<<dim3(16, 16, 2), dim3(256), 0, stream>>>(NNb, ZNb, rowp, colp, diag);
  loss_part<<<dim3(64), dim3(256), 0, stream>>>(rowp, colp, diag, lpart);
  loss_final<<<dim3(1), dim3(64), 0, stream>>>(lpart, out);
}